// Round 1
// baseline (4387.814 us; speedup 1.0000x reference)
//
#include <hip/hip_runtime.h>

#define WAY   100
#define SHOT  5
#define NQ    15
#define DD    4096
#define N_L   500
#define N_U   1500
#define N_TOT 2000
#define LAMF  10.0f
#define EPSF  1e-6f
#define MAXIT 1000

// ---- workspace layout (float offsets) ----
#define OFF_Z     0u                 // 2048*4096
#define OFF_MEANL 8388608u           // 4096
#define OFF_MEANU 8392704u           // 4096
#define OFF_SL    8396800u           // 100*4096
#define OFF_MUSA  8806400u           // 112*4096
#define OFF_MUSB  9265152u           // 112*4096
#define OFF_MUSQ  9723904u           // 128
#define OFF_KMAT  9724032u           // 150000
#define OFF_PMAT  9874032u           // 150000
#define OFF_COLS  10024032u          // 3*100*32 = 9600
#define OFF_MISC  10033632u          // [0..2]=err3(u), [3]=Ksum(f), [4]=cnt(u), [5]=gen(u), [6]=ctr(u)
#define OFF_D2P   10033664u          // 16*1536*112 = 2752512 (shared with CP: 4*100*4096)

#define G1_SPLIT 16
#define G1_KLEN  256                 // 4096/16
#define D2P_STRIDE 172032u           // 1536*112
#define CP_STRIDE  409600u           // 100*4096
#define SINK_BLOCKS 125
#define RPB 12                       // rows per sinkhorn block

// ---------------- preprocessing ----------------
__global__ __launch_bounds__(256) void k_pow_norm(const float* __restrict__ X, float* __restrict__ Z) {
  int i = blockIdx.x, tid = threadIdx.x;
  __shared__ float red[256];
  const float* x = X + (size_t)i * DD;
  float s = 0.f;
  for (int k = tid; k < DD; k += 256) s += x[k] + 1e-6f;
  red[tid] = s; __syncthreads();
  for (int o = 128; o > 0; o >>= 1) { if (tid < o) red[tid] += red[tid + o]; __syncthreads(); }
  float inv = 1.0f / fmaxf(sqrtf(red[0]), 1e-12f);
  float* z = Z + (size_t)i * DD;
  for (int k = tid; k < DD; k += 256) z[k] = sqrtf(x[k] + 1e-6f) * inv;
}

__global__ __launch_bounds__(256) void k_colmeans(const float* __restrict__ Z, float* __restrict__ mL, float* __restrict__ mU) {
  int k = blockIdx.x * 256 + threadIdx.x;  // grid 16 -> 4096
  float sL = 0.f, sU = 0.f;
  for (int i = 0; i < N_L; ++i)      sL += Z[(size_t)i * DD + k];
  for (int i = N_L; i < N_TOT; ++i)  sU += Z[(size_t)i * DD + k];
  mL[k] = sL / 500.0f;
  mU[k] = sU / 1500.0f;
}

__global__ __launch_bounds__(256) void k_center(float* __restrict__ Z, const float* __restrict__ mL, const float* __restrict__ mU) {
  int i = blockIdx.x, tid = threadIdx.x;
  __shared__ float red[256];
  const float* m = (i < N_L) ? mL : mU;
  float* z = Z + (size_t)i * DD;
  float s = 0.f;
  for (int k = tid; k < DD; k += 256) { float v = z[k] - m[k]; s += v * v; }
  red[tid] = s; __syncthreads();
  for (int o = 128; o > 0; o >>= 1) { if (tid < o) red[tid] += red[tid + o]; __syncthreads(); }
  float inv = 1.0f / fmaxf(sqrtf(red[0]), 1e-12f);
  for (int k = tid; k < DD; k += 256) z[k] = (z[k] - m[k]) * inv;
}

__global__ __launch_bounds__(256) void k_musinit(const float* __restrict__ Z, float* __restrict__ SL,
                                                 float* __restrict__ mus, float* __restrict__ musq) {
  int w = blockIdx.x, tid = threadIdx.x;
  __shared__ float red[256];
  float q = 0.f;
  for (int k = tid; k < DD; k += 256) {
    float s = 0.f;
    for (int sh = 0; sh < SHOT; ++sh) s += Z[(size_t)(sh * WAY + w) * DD + k];
    SL[(size_t)w * DD + k] = s;
    float m = s / 5.0f;
    mus[(size_t)w * DD + k] = m;
    q += m * m;
  }
  red[tid] = q; __syncthreads();
  for (int o = 128; o > 0; o >>= 1) { if (tid < o) red[tid] += red[tid + o]; __syncthreads(); }
  if (tid == 0) musq[w] = red[0];
}

// ---------------- GEMM1: partial dots Zu(1536x4096) x mus^T(112x4096) ----------------
__global__ __launch_bounds__(256) void k_gemm1(const float* __restrict__ Zu, const float* __restrict__ mus,
                                               float* __restrict__ D2P) {
  __shared__ __align__(16) float At[32][68];
  __shared__ __align__(16) float Bt[32][116];
  int m0 = blockIdx.x * 64;
  int sp = blockIdx.y;
  int k0 = sp * G1_KLEN;
  int tid = threadIdx.x;
  int tx = tid & 15, ty = tid >> 4;
  float acc[4][7];
#pragma unroll
  for (int i = 0; i < 4; ++i)
#pragma unroll
    for (int c = 0; c < 7; ++c) acc[i][c] = 0.f;

  for (int kc = 0; kc < G1_KLEN; kc += 32) {
    int kb = k0 + kc;
    int kk = tid & 31, rr = tid >> 5;
#pragma unroll
    for (int p = 0; p < 8; ++p) {
      int r = p * 8 + rr;
      At[kk][r] = Zu[(size_t)(m0 + r) * DD + kb + kk];
    }
#pragma unroll
    for (int p = 0; p < 14; ++p) {
      int j = p * 8 + rr;
      Bt[kk][j] = mus[(size_t)j * DD + kb + kk];
    }
    __syncthreads();
#pragma unroll 4
    for (int k = 0; k < 32; ++k) {
      const float4 a4 = *(const float4*)&At[k][ty * 4];
      float av[4] = {a4.x, a4.y, a4.z, a4.w};
      float bv[7];
#pragma unroll
      for (int c = 0; c < 7; ++c) bv[c] = Bt[k][tx + 16 * c];
#pragma unroll
      for (int i = 0; i < 4; ++i)
#pragma unroll
        for (int c = 0; c < 7; ++c) acc[i][c] = fmaf(av[i], bv[c], acc[i][c]);
    }
    __syncthreads();
  }
  float* dst = D2P + (size_t)sp * D2P_STRIDE;
#pragma unroll
  for (int i = 0; i < 4; ++i)
#pragma unroll
    for (int c = 0; c < 7; ++c)
      dst[(size_t)(m0 + ty * 4 + i) * 112 + tx + 16 * c] = acc[i][c];
}

// ---------------- reduce splits -> K = exp(-lam*dist); also zero sinkhorn scratch ----------------
__global__ __launch_bounds__(256) void k_expK(const float* __restrict__ D2P, const float* __restrict__ musq,
                                              float* __restrict__ Kmat, float* __restrict__ cols,
                                              unsigned* __restrict__ misc_u) {
  if (blockIdx.x == 0) {
    for (int z = threadIdx.x; z < 9600; z += 256) cols[z] = 0.f;
    if (threadIdx.x < 16) misc_u[threadIdx.x] = 0u;
  }
  int idx = blockIdx.x * 256 + threadIdx.x;
  if (idx < N_U * WAY) {
    int u = idx / WAY, j = idx - u * WAY;
    float s = 0.f;
#pragma unroll
    for (int sp = 0; sp < G1_SPLIT; ++sp) s += D2P[(size_t)sp * D2P_STRIDE + (size_t)u * 112 + j];
    float d2 = 1.0f + musq[j] - 2.0f * s;
    Kmat[idx] = expf(-LAMF * sqrtf(fmaxf(d2, 1e-12f)));
  }
}

// ---------------- sinkhorn (single kernel, device-scope barrier) ----------------
__device__ __forceinline__ void grid_barrier(unsigned* cnt, unsigned* gen, unsigned nb) {
  __syncthreads();
  if (threadIdx.x == 0) {
    __threadfence();
    unsigned g = __hip_atomic_load(gen, __ATOMIC_RELAXED, __HIP_MEMORY_SCOPE_AGENT);
    unsigned a = __hip_atomic_fetch_add(cnt, 1u, __ATOMIC_ACQ_REL, __HIP_MEMORY_SCOPE_AGENT);
    if (a == nb - 1u) {
      __hip_atomic_store(cnt, 0u, __ATOMIC_RELAXED, __HIP_MEMORY_SCOPE_AGENT);
      __hip_atomic_fetch_add(gen, 1u, __ATOMIC_RELEASE, __HIP_MEMORY_SCOPE_AGENT);
    } else {
      while (__hip_atomic_load(gen, __ATOMIC_ACQUIRE, __HIP_MEMORY_SCOPE_AGENT) == g) {
        __builtin_amdgcn_s_sleep(4);
      }
    }
    __threadfence();
  }
  __syncthreads();
}

__global__ __launch_bounds__(128) void k_sink(const float* __restrict__ Kg, float* __restrict__ Pg,
                                              float* __restrict__ cols, unsigned* __restrict__ misc_u,
                                              float* __restrict__ misc_f) {
  __shared__ float Kl[RPB * WAY];
  __shared__ float a[RPB], aold[RPB], prevs[RPB], b[WAY];
  __shared__ float red[128];
  __shared__ unsigned eloc;
  unsigned* errG = misc_u;
  float* KsumG = misc_f + 3;
  unsigned* cnt = misc_u + 4;
  unsigned* gen = misc_u + 5;
  int tid = threadIdx.x;
  int row0 = blockIdx.x * RPB;

  float ks = 0.f;
  for (int idx = tid; idx < RPB * WAY; idx += 128) { float v = Kg[row0 * WAY + idx]; Kl[idx] = v; ks += v; }
  red[tid] = ks; __syncthreads();
  for (int o = 64; o > 0; o >>= 1) { if (tid < o) red[tid] += red[tid + o]; __syncthreads(); }
  if (tid == 0) atomicAdd(KsumG, red[0]);
  if (tid < RPB) prevs[tid] = 0.f;
  if (tid < WAY) b[tid] = 1.0f;
  grid_barrier(cnt, gen, SINK_BLOCKS);
  float S = *KsumG;
  if (tid < RPB) a[tid] = 1.0f / S;   // folds K/K.sum() into a exactly

  bool conv = false;
  for (int t = 0; t < MAXIT; ++t) {
    int buf = t % 3;
    int zb = (t + 1) % 3;
    if (tid == 0) eloc = 0u;
    __syncthreads();                       // b, a stable; eloc zeroed
    if (tid < RPB) {
      const float* kr = &Kl[tid * WAY];
      float r0 = 0.f, r1 = 0.f, r2 = 0.f, r3 = 0.f;
#pragma unroll 4
      for (int j = 0; j < WAY; j += 4) {
        r0 = fmaf(kr[j], b[j], r0);
        r1 = fmaf(kr[j + 1], b[j + 1], r1);
        r2 = fmaf(kr[j + 2], b[j + 2], r2);
        r3 = fmaf(kr[j + 3], b[j + 3], r3);
      }
      float rs = ((r0 + r1) + (r2 + r3)) * a[tid];
      float e = fabsf(prevs[tid] - rs);
      aold[tid] = a[tid];
      a[tid] = a[tid] / rs;                // speculative; rolled back on convergence
      prevs[tid] = rs;
      atomicMax(&eloc, __float_as_uint(e));
    }
    __syncthreads();
    if (tid == 0) atomicMax(&errG[buf], eloc);
    if (tid < WAY) {
      float pc = 0.f;
#pragma unroll
      for (int r = 0; r < RPB; ++r) pc = fmaf(Kl[r * WAY + tid], a[r], pc);
      atomicAdd(&cols[buf * 3200 + tid * 32], pc);
    }
    if (blockIdx.x == 0) {
      if (tid < WAY) cols[zb * 3200 + tid * 32] = 0.f;   // safe: last read 2 barriers ago
      if (tid == 0) __hip_atomic_store(&errG[zb], 0u, __ATOMIC_RELAXED, __HIP_MEMORY_SCOPE_AGENT);
    }
    grid_barrier(cnt, gen, SINK_BLOCKS);
    unsigned eu = __hip_atomic_load(&errG[buf], __ATOMIC_RELAXED, __HIP_MEMORY_SCOPE_AGENT);
    if (__uint_as_float(eu) <= EPSF) { conv = true; break; }
    if (tid < WAY) b[tid] = (float)NQ / cols[buf * 3200 + tid * 32];
  }
  __syncthreads();
  for (int idx = tid; idx < RPB * WAY; idx += 128) {
    int r = idx / WAY; int j = idx - r * WAY;
    float av = conv ? aold[r] : a[r];
    Pg[row0 * WAY + idx] = av * Kl[idx] * b[j];
  }
}

// ---------------- GEMM2: CP[us] += Pu^T x Zu (split over u) ----------------
__global__ __launch_bounds__(256) void k_gemm2(const float* __restrict__ P, const float* __restrict__ Zu,
                                               float* __restrict__ CP) {
  int k = blockIdx.x * 256 + threadIdx.x;   // 16 * 256 = 4096
  int w0 = blockIdx.y * 10;                 // 10 blocks
  int u0 = blockIdx.z * 375;                // 4 splits
  __shared__ __align__(16) float Pl[75][12];
  float acc[10];
#pragma unroll
  for (int c = 0; c < 10; ++c) acc[c] = 0.f;
  for (int ch = 0; ch < 5; ++ch) {
    int ub = u0 + ch * 75;
    __syncthreads();
    for (int idx = threadIdx.x; idx < 750; idx += 256) {
      int uu = idx / 10, cc = idx - uu * 10;
      Pl[uu][cc] = P[(size_t)(ub + uu) * WAY + w0 + cc];
    }
    __syncthreads();
    for (int u = 0; u < 75; ++u) {
      float z = Zu[(size_t)(ub + u) * DD + k];
      const float* pr = &Pl[u][0];
      const float4 p0 = *(const float4*)pr;
      const float4 p1 = *(const float4*)(pr + 4);
      const float2 p2 = *(const float2*)(pr + 8);
      acc[0] = fmaf(p0.x, z, acc[0]); acc[1] = fmaf(p0.y, z, acc[1]);
      acc[2] = fmaf(p0.z, z, acc[2]); acc[3] = fmaf(p0.w, z, acc[3]);
      acc[4] = fmaf(p1.x, z, acc[4]); acc[5] = fmaf(p1.y, z, acc[5]);
      acc[6] = fmaf(p1.z, z, acc[6]); acc[7] = fmaf(p1.w, z, acc[7]);
      acc[8] = fmaf(p2.x, z, acc[8]); acc[9] = fmaf(p2.y, z, acc[9]);
    }
  }
  float* dst = CP + (size_t)blockIdx.z * CP_STRIDE;
#pragma unroll
  for (int c = 0; c < 10; ++c) dst[(size_t)(w0 + c) * DD + k] = acc[c];
}

// ---------------- mus update + musq ----------------
__global__ __launch_bounds__(256) void k_musup(const float* __restrict__ musR, const float* __restrict__ SL,
                                               const float* __restrict__ CP, float* __restrict__ musW,
                                               float* __restrict__ musq) {
  int w = blockIdx.x, tid = threadIdx.x;
  __shared__ float red[256];
  float q = 0.f;
  for (int k = tid; k < DD; k += 256) {
    size_t o = (size_t)w * DD + k;
    float c2 = CP[o] + CP[CP_STRIDE + o] + CP[2 * CP_STRIDE + o] + CP[3 * CP_STRIDE + o];
    float emus = (SL[o] + c2) / 20.0f;   // p.sum(0) == 5 + 15 exactly
    float m = musR[o];
    float v = m + 0.2f * (emus - m);
    musW[o] = v;
    q += v * v;
  }
  red[tid] = q; __syncthreads();
  for (int o = 128; o > 0; o >>= 1) { if (tid < o) red[tid] += red[tid + o]; __syncthreads(); }
  if (tid == 0) musq[w] = red[0];
}

// ---------------- final logP + acc ----------------
__global__ __launch_bounds__(128) void k_final(const float* __restrict__ Pg, const int* __restrict__ labels,
                                               float* __restrict__ out, unsigned* __restrict__ ctr) {
  int u = blockIdx.x, tid = threadIdx.x;
  __shared__ float vals[WAY];
  if (tid < WAY) {
    float v = Pg[(size_t)u * WAY + tid];
    vals[tid] = v;
    out[(size_t)u * WAY + tid] = logf(v + 1e-5f);
  }
  __syncthreads();
  if (tid == 0) {
    int am = 0; float bv = vals[0];
    for (int j = 1; j < WAY; ++j) { if (vals[j] > bv) { bv = vals[j]; am = j; } }
    if (am == labels[N_L + u]) atomicAdd(ctr, 1u);
  }
}

__global__ void k_acc(const unsigned* __restrict__ ctr, float* __restrict__ out) {
  if (threadIdx.x == 0) out[N_U * WAY] = (float)(*ctr) / 1500.0f;
}

// ---------------- host ----------------
extern "C" void kernel_launch(void* const* d_in, const int* in_sizes, int n_in,
                              void* d_out, int out_size, void* d_ws, size_t ws_size,
                              hipStream_t stream) {
  const float* X = (const float*)d_in[0];
  const int* labels = (const int*)d_in[1];
  float* out = (float*)d_out;
  float* ws = (float*)d_ws;

  float* Z     = ws + OFF_Z;
  float* Zu    = Z + (size_t)N_L * DD;
  float* meanL = ws + OFF_MEANL;
  float* meanU = ws + OFF_MEANU;
  float* SL    = ws + OFF_SL;
  float* musA  = ws + OFF_MUSA;
  float* musB  = ws + OFF_MUSB;
  float* musq  = ws + OFF_MUSQ;
  float* Kmat  = ws + OFF_KMAT;
  float* Pmat  = ws + OFF_PMAT;
  float* cols  = ws + OFF_COLS;
  float* misc_f = ws + OFF_MISC;
  unsigned* misc_u = (unsigned*)(ws + OFF_MISC);
  float* D2P   = ws + OFF_D2P;
  float* CP    = ws + OFF_D2P;   // overlaid: disjoint lifetimes within an epoch

  k_pow_norm<<<N_TOT, 256, 0, stream>>>(X, Z);
  k_colmeans<<<16, 256, 0, stream>>>(Z, meanL, meanU);
  k_center<<<N_TOT, 256, 0, stream>>>(Z, meanL, meanU);
  k_musinit<<<WAY, 256, 0, stream>>>(Z, SL, musA, musq);

  float* musR = musA;
  float* musW = musB;
  for (int e = 0; e < 20; ++e) {
    k_gemm1<<<dim3(24, G1_SPLIT), 256, 0, stream>>>(Zu, musR, D2P);
    k_expK<<<586, 256, 0, stream>>>(D2P, musq, Kmat, cols, misc_u);
    k_sink<<<SINK_BLOCKS, 128, 0, stream>>>(Kmat, Pmat, cols, misc_u, misc_f);
    k_gemm2<<<dim3(16, 10, 4), 256, 0, stream>>>(Pmat, Zu, CP);
    k_musup<<<WAY, 256, 0, stream>>>(musR, SL, CP, musW, musq);
    float* tmp = musR; musR = musW; musW = tmp;
  }
  k_gemm1<<<dim3(24, G1_SPLIT), 256, 0, stream>>>(Zu, musR, D2P);
  k_expK<<<586, 256, 0, stream>>>(D2P, musq, Kmat, cols, misc_u);
  k_sink<<<SINK_BLOCKS, 128, 0, stream>>>(Kmat, Pmat, cols, misc_u, misc_f);
  k_final<<<N_U, 128, 0, stream>>>(Pmat, labels, out, misc_u + 6);
  k_acc<<<1, 64, 0, stream>>>(misc_u + 6, out);
}

// Round 2
// 3370.629 us; speedup vs baseline: 1.3018x; 1.3018x over previous
//
#include <hip/hip_runtime.h>

#define WAY   100
#define SHOT  5
#define NQ    15
#define DD    4096
#define N_L   500
#define N_U   1500
#define N_TOT 2000
#define LAMF  10.0f
#define EPSF  1e-6f
#define MAXIT 1000

// ---- workspace layout (float offsets) ----
#define OFF_Z     0u                 // 2048*4096
#define OFF_MEANL 8388608u           // 4096
#define OFF_MEANU 8392704u           // 4096
#define OFF_SL    8396800u           // 100*4096
#define OFF_MUSA  8806400u           // 112*4096
#define OFF_MUSB  9265152u           // 112*4096
#define OFF_MUSQ  9723904u           // 128
#define OFF_KMAT  9724032u           // 150000
#define OFF_PMAT  9874032u           // 150000
#define OFF_COLS  10024032u          // 3*100*32 = 9600
#define OFF_MISC  10033632u          // [0..2]=err3(u), [3]=Ksum(f), [4]=cnt(u), [5]=gen(u), [6]=ctr(u)
#define OFF_D2P   10033664u          // 16*1536*112 = 2752512 (shared with CP: 4*100*4096)

#define G1_SPLIT 16
#define G1_KLEN  256                 // 4096/16
#define D2P_STRIDE 172032u           // 1536*112
#define CP_STRIDE  409600u           // 100*4096
#define SINK_BLOCKS 16               // R2: 125 -> 16; barrier arrival serialization was ~2.5us/iter
#define RPB 94                       // rows per sinkhorn block (16*94 = 1504 >= 1500)

// ---------------- preprocessing ----------------
__global__ __launch_bounds__(256) void k_pow_norm(const float* __restrict__ X, float* __restrict__ Z) {
  int i = blockIdx.x, tid = threadIdx.x;
  __shared__ float red[256];
  const float* x = X + (size_t)i * DD;
  float s = 0.f;
  for (int k = tid; k < DD; k += 256) s += x[k] + 1e-6f;
  red[tid] = s; __syncthreads();
  for (int o = 128; o > 0; o >>= 1) { if (tid < o) red[tid] += red[tid + o]; __syncthreads(); }
  float inv = 1.0f / fmaxf(sqrtf(red[0]), 1e-12f);
  float* z = Z + (size_t)i * DD;
  for (int k = tid; k < DD; k += 256) z[k] = sqrtf(x[k] + 1e-6f) * inv;
}

__global__ __launch_bounds__(256) void k_colmeans(const float* __restrict__ Z, float* __restrict__ mL, float* __restrict__ mU) {
  int k = blockIdx.x * 256 + threadIdx.x;  // grid 16 -> 4096
  float sL = 0.f, sU = 0.f;
  for (int i = 0; i < N_L; ++i)      sL += Z[(size_t)i * DD + k];
  for (int i = N_L; i < N_TOT; ++i)  sU += Z[(size_t)i * DD + k];
  mL[k] = sL / 500.0f;
  mU[k] = sU / 1500.0f;
}

__global__ __launch_bounds__(256) void k_center(float* __restrict__ Z, const float* __restrict__ mL, const float* __restrict__ mU) {
  int i = blockIdx.x, tid = threadIdx.x;
  __shared__ float red[256];
  const float* m = (i < N_L) ? mL : mU;
  float* z = Z + (size_t)i * DD;
  float s = 0.f;
  for (int k = tid; k < DD; k += 256) { float v = z[k] - m[k]; s += v * v; }
  red[tid] = s; __syncthreads();
  for (int o = 128; o > 0; o >>= 1) { if (tid < o) red[tid] += red[tid + o]; __syncthreads(); }
  float inv = 1.0f / fmaxf(sqrtf(red[0]), 1e-12f);
  for (int k = tid; k < DD; k += 256) z[k] = (z[k] - m[k]) * inv;
}

__global__ __launch_bounds__(256) void k_musinit(const float* __restrict__ Z, float* __restrict__ SL,
                                                 float* __restrict__ mus, float* __restrict__ musq) {
  int w = blockIdx.x, tid = threadIdx.x;
  __shared__ float red[256];
  float q = 0.f;
  for (int k = tid; k < DD; k += 256) {
    float s = 0.f;
    for (int sh = 0; sh < SHOT; ++sh) s += Z[(size_t)(sh * WAY + w) * DD + k];
    SL[(size_t)w * DD + k] = s;
    float m = s / 5.0f;
    mus[(size_t)w * DD + k] = m;
    q += m * m;
  }
  red[tid] = q; __syncthreads();
  for (int o = 128; o > 0; o >>= 1) { if (tid < o) red[tid] += red[tid + o]; __syncthreads(); }
  if (tid == 0) musq[w] = red[0];
}

// ---------------- GEMM1: partial dots Zu(1536x4096) x mus^T(112x4096) ----------------
__global__ __launch_bounds__(256) void k_gemm1(const float* __restrict__ Zu, const float* __restrict__ mus,
                                               float* __restrict__ D2P) {
  __shared__ __align__(16) float At[32][68];
  __shared__ __align__(16) float Bt[32][116];
  int m0 = blockIdx.x * 64;
  int sp = blockIdx.y;
  int k0 = sp * G1_KLEN;
  int tid = threadIdx.x;
  int tx = tid & 15, ty = tid >> 4;
  float acc[4][7];
#pragma unroll
  for (int i = 0; i < 4; ++i)
#pragma unroll
    for (int c = 0; c < 7; ++c) acc[i][c] = 0.f;

  for (int kc = 0; kc < G1_KLEN; kc += 32) {
    int kb = k0 + kc;
    int kk = tid & 31, rr = tid >> 5;
#pragma unroll
    for (int p = 0; p < 8; ++p) {
      int r = p * 8 + rr;
      At[kk][r] = Zu[(size_t)(m0 + r) * DD + kb + kk];
    }
#pragma unroll
    for (int p = 0; p < 14; ++p) {
      int j = p * 8 + rr;
      Bt[kk][j] = mus[(size_t)j * DD + kb + kk];
    }
    __syncthreads();
#pragma unroll 4
    for (int k = 0; k < 32; ++k) {
      const float4 a4 = *(const float4*)&At[k][ty * 4];
      float av[4] = {a4.x, a4.y, a4.z, a4.w};
      float bv[7];
#pragma unroll
      for (int c = 0; c < 7; ++c) bv[c] = Bt[k][tx + 16 * c];
#pragma unroll
      for (int i = 0; i < 4; ++i)
#pragma unroll
        for (int c = 0; c < 7; ++c) acc[i][c] = fmaf(av[i], bv[c], acc[i][c]);
    }
    __syncthreads();
  }
  float* dst = D2P + (size_t)sp * D2P_STRIDE;
#pragma unroll
  for (int i = 0; i < 4; ++i)
#pragma unroll
    for (int c = 0; c < 7; ++c)
      dst[(size_t)(m0 + ty * 4 + i) * 112 + tx + 16 * c] = acc[i][c];
}

// ---------------- reduce splits -> K = exp(-lam*dist); also zero sinkhorn scratch ----------------
__global__ __launch_bounds__(256) void k_expK(const float* __restrict__ D2P, const float* __restrict__ musq,
                                              float* __restrict__ Kmat, float* __restrict__ cols,
                                              unsigned* __restrict__ misc_u) {
  if (blockIdx.x == 0) {
    for (int z = threadIdx.x; z < 9600; z += 256) cols[z] = 0.f;
    if (threadIdx.x < 16) misc_u[threadIdx.x] = 0u;
  }
  int idx = blockIdx.x * 256 + threadIdx.x;
  if (idx < N_U * WAY) {
    int u = idx / WAY, j = idx - u * WAY;
    float s = 0.f;
#pragma unroll
    for (int sp = 0; sp < G1_SPLIT; ++sp) s += D2P[(size_t)sp * D2P_STRIDE + (size_t)u * 112 + j];
    float d2 = 1.0f + musq[j] - 2.0f * s;
    Kmat[idx] = expf(-LAMF * sqrtf(fmaxf(d2, 1e-12f)));
  }
}

// ---------------- sinkhorn (single kernel, device-scope barrier) ----------------
__device__ __forceinline__ void grid_barrier(unsigned* cnt, unsigned* gen, unsigned nb) {
  __syncthreads();
  if (threadIdx.x == 0) {
    __threadfence();
    unsigned g = __hip_atomic_load(gen, __ATOMIC_RELAXED, __HIP_MEMORY_SCOPE_AGENT);
    unsigned a = __hip_atomic_fetch_add(cnt, 1u, __ATOMIC_ACQ_REL, __HIP_MEMORY_SCOPE_AGENT);
    if (a == nb - 1u) {
      __hip_atomic_store(cnt, 0u, __ATOMIC_RELAXED, __HIP_MEMORY_SCOPE_AGENT);
      __hip_atomic_fetch_add(gen, 1u, __ATOMIC_RELEASE, __HIP_MEMORY_SCOPE_AGENT);
    } else {
      while (__hip_atomic_load(gen, __ATOMIC_ACQUIRE, __HIP_MEMORY_SCOPE_AGENT) == g) {
        __builtin_amdgcn_s_sleep(1);
      }
    }
    __threadfence();
  }
  __syncthreads();
}

__global__ __launch_bounds__(256) void k_sink(const float* __restrict__ Kg, float* __restrict__ Pg,
                                              float* __restrict__ cols, unsigned* __restrict__ misc_u,
                                              float* __restrict__ misc_f) {
  __shared__ float Kl[RPB * WAY];                // 37.6 KB
  __shared__ float a[RPB], aold[RPB], prevs[RPB], b[WAY];
  __shared__ float rerr[256];
  __shared__ float c2[2 * WAY];
  __shared__ float red[256];
  unsigned* errG = misc_u;
  float* KsumG = misc_f + 3;
  unsigned* cnt = misc_u + 4;
  unsigned* gen = misc_u + 5;
  int tid = threadIdx.x;
  int row0 = blockIdx.x * RPB;
  int nrows = (row0 + RPB <= N_U) ? RPB : (N_U - row0);   // last block: 90

  float ks = 0.f;
  for (int idx = tid; idx < nrows * WAY; idx += 256) { float v = Kg[row0 * WAY + idx]; Kl[idx] = v; ks += v; }
  red[tid] = ks; __syncthreads();
  for (int o = 128; o > 0; o >>= 1) { if (tid < o) red[tid] += red[tid + o]; __syncthreads(); }
  if (tid == 0) atomicAdd(KsumG, red[0]);
  if (tid < RPB) prevs[tid] = 0.f;
  if (tid < WAY) b[tid] = 1.0f;
  grid_barrier(cnt, gen, SINK_BLOCKS);
  float S = *KsumG;
  if (tid < RPB) a[tid] = 1.0f / S;   // folds K/K.sum() into a exactly

  bool conv = false;
  for (int t = 0; t < MAXIT; ++t) {
    int buf = t % 3;
    int zb = (t + 1) % 3;
    __syncthreads();                       // b stable from previous readback
    if (tid < nrows) {
      const float* kr = &Kl[tid * WAY];
      float r0 = 0.f, r1 = 0.f, r2 = 0.f, r3 = 0.f;
#pragma unroll 4
      for (int j = 0; j < WAY; j += 4) {
        r0 = fmaf(kr[j], b[j], r0);
        r1 = fmaf(kr[j + 1], b[j + 1], r1);
        r2 = fmaf(kr[j + 2], b[j + 2], r2);
        r3 = fmaf(kr[j + 3], b[j + 3], r3);
      }
      float rs = ((r0 + r1) + (r2 + r3)) * a[tid];
      rerr[tid] = fabsf(prevs[tid] - rs);
      aold[tid] = a[tid];
      a[tid] = a[tid] / rs;                // speculative; rolled back on convergence
      prevs[tid] = rs;
    } else {
      rerr[tid] = 0.f;
    }
    __syncthreads();                       // new a[] + rerr complete
    // column partials with new a: threads 0-99 rows [0,47), threads 128-227 rows [47,94)
    {
      int j = -1, rlo = 0, rhi = 0, slot = 0;
      if (tid < WAY) { j = tid; rlo = 0; rhi = 47; slot = 0; }
      else if (tid >= 128 && tid < 128 + WAY) { j = tid - 128; rlo = 47; rhi = RPB; slot = 1; }
      if (j >= 0) {
        if (rhi > nrows) rhi = nrows;
        float pc = 0.f;
        for (int r = rlo; r < rhi; ++r) pc = fmaf(Kl[r * WAY + j], a[r], pc);
        c2[slot * WAY + j] = pc;
      }
    }
    __syncthreads();
    if (tid < WAY) atomicAdd(&cols[buf * 3200 + tid * 32], c2[tid] + c2[WAY + tid]);
    if (blockIdx.x == 0) {
      if (tid < WAY) cols[zb * 3200 + tid * 32] = 0.f;   // safe: last read 2 barriers ago
      if (tid == 0) __hip_atomic_store(&errG[zb], 0u, __ATOMIC_RELAXED, __HIP_MEMORY_SCOPE_AGENT);
    }
    if (tid < 64) {
      float m = fmaxf(fmaxf(rerr[tid], rerr[tid + 64]), fmaxf(rerr[tid + 128], rerr[tid + 192]));
#pragma unroll
      for (int o = 32; o > 0; o >>= 1) m = fmaxf(m, __shfl_down(m, o));
      if (tid == 0) atomicMax(&errG[buf], __float_as_uint(m));
    }
    grid_barrier(cnt, gen, SINK_BLOCKS);
    unsigned eu = __hip_atomic_load(&errG[buf], __ATOMIC_RELAXED, __HIP_MEMORY_SCOPE_AGENT);
    if (__uint_as_float(eu) <= EPSF) { conv = true; break; }
    if (tid < WAY) b[tid] = (float)NQ / cols[buf * 3200 + tid * 32];
  }
  __syncthreads();
  for (int idx = tid; idx < nrows * WAY; idx += 256) {
    int r = idx / WAY; int j = idx - r * WAY;
    float av = conv ? aold[r] : a[r];
    Pg[row0 * WAY + idx] = av * Kl[idx] * b[j];
  }
}

// ---------------- GEMM2: CP[us] += Pu^T x Zu (split over u) ----------------
__global__ __launch_bounds__(256) void k_gemm2(const float* __restrict__ P, const float* __restrict__ Zu,
                                               float* __restrict__ CP) {
  int k = blockIdx.x * 256 + threadIdx.x;   // 16 * 256 = 4096
  int w0 = blockIdx.y * 10;                 // 10 blocks
  int u0 = blockIdx.z * 375;                // 4 splits
  __shared__ __align__(16) float Pl[75][12];
  float acc[10];
#pragma unroll
  for (int c = 0; c < 10; ++c) acc[c] = 0.f;
  for (int ch = 0; ch < 5; ++ch) {
    int ub = u0 + ch * 75;
    __syncthreads();
    for (int idx = threadIdx.x; idx < 750; idx += 256) {
      int uu = idx / 10, cc = idx - uu * 10;
      Pl[uu][cc] = P[(size_t)(ub + uu) * WAY + w0 + cc];
    }
    __syncthreads();
    for (int u = 0; u < 75; ++u) {
      float z = Zu[(size_t)(ub + u) * DD + k];
      const float* pr = &Pl[u][0];
      const float4 p0 = *(const float4*)pr;
      const float4 p1 = *(const float4*)(pr + 4);
      const float2 p2 = *(const float2*)(pr + 8);
      acc[0] = fmaf(p0.x, z, acc[0]); acc[1] = fmaf(p0.y, z, acc[1]);
      acc[2] = fmaf(p0.z, z, acc[2]); acc[3] = fmaf(p0.w, z, acc[3]);
      acc[4] = fmaf(p1.x, z, acc[4]); acc[5] = fmaf(p1.y, z, acc[5]);
      acc[6] = fmaf(p1.z, z, acc[6]); acc[7] = fmaf(p1.w, z, acc[7]);
      acc[8] = fmaf(p2.x, z, acc[8]); acc[9] = fmaf(p2.y, z, acc[9]);
    }
  }
  float* dst = CP + (size_t)blockIdx.z * CP_STRIDE;
#pragma unroll
  for (int c = 0; c < 10; ++c) dst[(size_t)(w0 + c) * DD + k] = acc[c];
}

// ---------------- mus update + musq ----------------
__global__ __launch_bounds__(256) void k_musup(const float* __restrict__ musR, const float* __restrict__ SL,
                                               const float* __restrict__ CP, float* __restrict__ musW,
                                               float* __restrict__ musq) {
  int w = blockIdx.x, tid = threadIdx.x;
  __shared__ float red[256];
  float q = 0.f;
  for (int k = tid; k < DD; k += 256) {
    size_t o = (size_t)w * DD + k;
    float c2 = CP[o] + CP[CP_STRIDE + o] + CP[2 * CP_STRIDE + o] + CP[3 * CP_STRIDE + o];
    float emus = (SL[o] + c2) / 20.0f;   // p.sum(0) == 5 + 15 exactly
    float m = musR[o];
    float v = m + 0.2f * (emus - m);
    musW[o] = v;
    q += v * v;
  }
  red[tid] = q; __syncthreads();
  for (int o = 128; o > 0; o >>= 1) { if (tid < o) red[tid] += red[tid + o]; __syncthreads(); }
  if (tid == 0) musq[w] = red[0];
}

// ---------------- final logP + acc ----------------
__global__ __launch_bounds__(128) void k_final(const float* __restrict__ Pg, const int* __restrict__ labels,
                                               float* __restrict__ out, unsigned* __restrict__ ctr) {
  int u = blockIdx.x, tid = threadIdx.x;
  __shared__ float vals[WAY];
  if (tid < WAY) {
    float v = Pg[(size_t)u * WAY + tid];
    vals[tid] = v;
    out[(size_t)u * WAY + tid] = logf(v + 1e-5f);
  }
  __syncthreads();
  if (tid == 0) {
    int am = 0; float bv = vals[0];
    for (int j = 1; j < WAY; ++j) { if (vals[j] > bv) { bv = vals[j]; am = j; } }
    if (am == labels[N_L + u]) atomicAdd(ctr, 1u);
  }
}

__global__ void k_acc(const unsigned* __restrict__ ctr, float* __restrict__ out) {
  if (threadIdx.x == 0) out[N_U * WAY] = (float)(*ctr) / 1500.0f;
}

// ---------------- host ----------------
extern "C" void kernel_launch(void* const* d_in, const int* in_sizes, int n_in,
                              void* d_out, int out_size, void* d_ws, size_t ws_size,
                              hipStream_t stream) {
  const float* X = (const float*)d_in[0];
  const int* labels = (const int*)d_in[1];
  float* out = (float*)d_out;
  float* ws = (float*)d_ws;

  float* Z     = ws + OFF_Z;
  float* Zu    = Z + (size_t)N_L * DD;
  float* meanL = ws + OFF_MEANL;
  float* meanU = ws + OFF_MEANU;
  float* SL    = ws + OFF_SL;
  float* musA  = ws + OFF_MUSA;
  float* musB  = ws + OFF_MUSB;
  float* musq  = ws + OFF_MUSQ;
  float* Kmat  = ws + OFF_KMAT;
  float* Pmat  = ws + OFF_PMAT;
  float* cols  = ws + OFF_COLS;
  float* misc_f = ws + OFF_MISC;
  unsigned* misc_u = (unsigned*)(ws + OFF_MISC);
  float* D2P   = ws + OFF_D2P;
  float* CP    = ws + OFF_D2P;   // overlaid: disjoint lifetimes within an epoch

  k_pow_norm<<<N_TOT, 256, 0, stream>>>(X, Z);
  k_colmeans<<<16, 256, 0, stream>>>(Z, meanL, meanU);
  k_center<<<N_TOT, 256, 0, stream>>>(Z, meanL, meanU);
  k_musinit<<<WAY, 256, 0, stream>>>(Z, SL, musA, musq);

  float* musR = musA;
  float* musW = musB;
  for (int e = 0; e < 20; ++e) {
    k_gemm1<<<dim3(24, G1_SPLIT), 256, 0, stream>>>(Zu, musR, D2P);
    k_expK<<<586, 256, 0, stream>>>(D2P, musq, Kmat, cols, misc_u);
    k_sink<<<SINK_BLOCKS, 256, 0, stream>>>(Kmat, Pmat, cols, misc_u, misc_f);
    k_gemm2<<<dim3(16, 10, 4), 256, 0, stream>>>(Pmat, Zu, CP);
    k_musup<<<WAY, 256, 0, stream>>>(musR, SL, CP, musW, musq);
    float* tmp = musR; musR = musW; musW = tmp;
  }
  k_gemm1<<<dim3(24, G1_SPLIT), 256, 0, stream>>>(Zu, musR, D2P);
  k_expK<<<586, 256, 0, stream>>>(D2P, musq, Kmat, cols, misc_u);
  k_sink<<<SINK_BLOCKS, 256, 0, stream>>>(Kmat, Pmat, cols, misc_u, misc_f);
  k_final<<<N_U, 128, 0, stream>>>(Pmat, labels, out, misc_u + 6);
  k_acc<<<1, 64, 0, stream>>>(misc_u + 6, out);
}

// Round 3
// 2536.346 us; speedup vs baseline: 1.7300x; 1.3289x over previous
//
#include <hip/hip_runtime.h>

#define WAY   100
#define SHOT  5
#define NQ    15
#define DD    4096
#define N_L   500
#define N_U   1500
#define N_TOT 2000
#define LAMF  10.0f
#define EPSF  1e-6f
#define MAXIT 1000

// ---- workspace layout (float offsets) ----
#define OFF_Z     0u                 // 2048*4096
#define OFF_MEANL 8388608u           // 4096 (raw col sums, labeled)
#define OFF_MEANU 8392704u           // 4096 (raw col sums, unlabeled)
#define OFF_SL    8396800u           // 100*4096
#define OFF_MUSA  8806400u           // 112*4096
#define OFF_MUSB  9265152u           // 112*4096
#define OFF_MUSQ  9723904u           // 128
#define OFF_KMAT  9724032u           // 150000
#define OFF_MUSB16 9724032u          // bf16 mus, 112*4096*2B = 229376 fw. Overlays Kmat/Pmat:
                                     //   written by musinit/musup, read by gemm1; expK then clobbers
                                     //   with Kmat, sink writes Pmat. Lifetimes verified disjoint.
#define OFF_PMAT  9874032u           // 150000
#define OFF_COLS  10024032u          // 3*100*32 = 9600
#define OFF_MISC  10033632u          // [0..2]=err3(u), [3]=Ksum(f), [4]=cnt(u), [5]=gen(u), [6]=ctr(u)
#define OFF_D2P   10033664u          // 16*112*1536 = 2752512 (transposed partials; shared with CP)

#define G1_SPLIT 16
#define G1_KLEN  256                 // 4096/16
#define D2P_STRIDE 172032u           // 112*1536
#define CP_STRIDE  409600u           // 100*4096
#define SINK_BLOCKS 16
#define RPB 94                       // rows per sinkhorn block (16*94 = 1504 >= 1500)

typedef __attribute__((ext_vector_type(8))) short short8_t;
typedef __attribute__((ext_vector_type(4))) float f32x4;

// fp32 -> bf16 bits, round-to-nearest-even (normal values)
__device__ __forceinline__ short f2bs(float f) {
  unsigned u = __float_as_uint(f);
  unsigned r = (u + 0x7FFFu + ((u >> 16) & 1u)) >> 16;
  return (short)r;
}

// ---------------- preprocessing ----------------
__global__ __launch_bounds__(256) void k_pow_norm(const float* __restrict__ X, float* __restrict__ Z,
                                                  float* __restrict__ msums) {
  int i = blockIdx.x, tid = threadIdx.x;
  __shared__ float red[256];
  if (i < 32) msums[i * 256 + tid] = 0.f;    // zero meanL+meanU raw sums (contiguous 8192)
  const float* x = X + (size_t)i * DD;
  float s = 0.f;
  for (int k = tid; k < DD; k += 256) s += x[k] + 1e-6f;
  red[tid] = s; __syncthreads();
  for (int o = 128; o > 0; o >>= 1) { if (tid < o) red[tid] += red[tid + o]; __syncthreads(); }
  float inv = 1.0f / fmaxf(sqrtf(red[0]), 1e-12f);
  float* z = Z + (size_t)i * DD;
  for (int k = tid; k < DD; k += 256) z[k] = sqrtf(x[k] + 1e-6f) * inv;
}

// R3: parallel column sums. grid (16, 25): 256 cols x 80 rows per block.
__global__ __launch_bounds__(256) void k_colmeans(const float* __restrict__ Z, float* __restrict__ mLs,
                                                  float* __restrict__ mUs) {
  int k = blockIdx.x * 256 + threadIdx.x;
  int r0 = blockIdx.y * 80;
  float sL = 0.f, sU = 0.f;
  for (int r = r0; r < r0 + 80; ++r) {
    float v = Z[(size_t)r * DD + k];
    if (r < N_L) sL += v; else sU += v;
  }
  if (r0 < N_L) atomicAdd(&mLs[k], sL);
  if (r0 + 80 > N_L) atomicAdd(&mUs[k], sU);
}

__global__ __launch_bounds__(256) void k_center(float* __restrict__ Z, const float* __restrict__ mLs,
                                                const float* __restrict__ mUs) {
  int i = blockIdx.x, tid = threadIdx.x;
  __shared__ float red[256];
  const float* m = (i < N_L) ? mLs : mUs;
  const float scale = (i < N_L) ? (1.0f / 500.0f) : (1.0f / 1500.0f);
  float* z = Z + (size_t)i * DD;
  float s = 0.f;
  for (int k = tid; k < DD; k += 256) { float v = z[k] - m[k] * scale; s += v * v; }
  red[tid] = s; __syncthreads();
  for (int o = 128; o > 0; o >>= 1) { if (tid < o) red[tid] += red[tid + o]; __syncthreads(); }
  float inv = 1.0f / fmaxf(sqrtf(red[0]), 1e-12f);
  for (int k = tid; k < DD; k += 256) z[k] = (z[k] - m[k] * scale) * inv;
}

__global__ __launch_bounds__(256) void k_musinit(const float* __restrict__ Z, float* __restrict__ SL,
                                                 float* __restrict__ mus, float* __restrict__ musq,
                                                 short* __restrict__ musb) {
  int w = blockIdx.x, tid = threadIdx.x;
  __shared__ float red[256];
  float q = 0.f;
  for (int k = tid; k < DD; k += 256) {
    float s = 0.f;
    for (int sh = 0; sh < SHOT; ++sh) s += Z[(size_t)(sh * WAY + w) * DD + k];
    SL[(size_t)w * DD + k] = s;
    float m = s / 5.0f;
    mus[(size_t)w * DD + k] = m;
    musb[(size_t)w * DD + k] = f2bs(m);
    q += m * m;
  }
  red[tid] = q; __syncthreads();
  for (int o = 128; o > 0; o >>= 1) { if (tid < o) red[tid] += red[tid + o]; __syncthreads(); }
  if (tid == 0) musq[w] = red[0];
}

// ---------------- GEMM1 (MFMA): C1T[w][u] = sum_k mus[w][k]*Zu[u][k], k-split partials ----------------
// A-operand = mus_b rows (bf16, preconverted); B-operand = Zu rows (fp32, converted in-register).
// Both operands k-contiguous per lane: A[m=lane&15][k=quad*8+j], B[n=lane&15][k=quad*8+j].
// D: row=(lane>>4)*4+reg (w within tile), col=lane&15 (u within tile).
__global__ __launch_bounds__(256) void k_gemm1(const float* __restrict__ Zu, const short* __restrict__ musb,
                                               float* __restrict__ D2PT) {
  int tid = threadIdx.x;
  int wv = tid >> 6;          // wave 0..3
  int l = tid & 63;
  int l15 = l & 15, quad = l >> 4;
  int u0 = blockIdx.x * 64 + wv * 16;          // 24 blocks -> u tiles
  int kz = blockIdx.y * G1_KLEN;               // 16 k-splits of 256
  f32x4 acc[7];
#pragma unroll
  for (int c = 0; c < 7; ++c) acc[c] = (f32x4){0.f, 0.f, 0.f, 0.f};

  const float* bp = Zu + (size_t)(u0 + l15) * DD + kz + quad * 8;
  const short* ap = musb + (size_t)l15 * DD + kz + quad * 8;

#pragma unroll 2
  for (int kc = 0; kc < G1_KLEN; kc += 32) {
    float4 v0 = *(const float4*)(bp + kc);
    float4 v1 = *(const float4*)(bp + kc + 4);
    short8_t bf;
    bf[0] = f2bs(v0.x); bf[1] = f2bs(v0.y); bf[2] = f2bs(v0.z); bf[3] = f2bs(v0.w);
    bf[4] = f2bs(v1.x); bf[5] = f2bs(v1.y); bf[6] = f2bs(v1.z); bf[7] = f2bs(v1.w);
#pragma unroll
    for (int c = 0; c < 7; ++c) {
      short8_t af = *(const short8_t*)(ap + (size_t)c * 16 * DD + kc);
      acc[c] = __builtin_amdgcn_mfma_f32_16x16x32_bf16(af, bf, acc[c], 0, 0, 0);
    }
  }
  float* dst = D2PT + (size_t)blockIdx.y * D2P_STRIDE;
#pragma unroll
  for (int c = 0; c < 7; ++c)
#pragma unroll
    for (int r = 0; r < 4; ++r)
      dst[(size_t)(16 * c + quad * 4 + r) * 1536 + u0 + l15] = acc[c][r];
}

// ---------------- reduce splits -> K = exp(-lam*dist); also zero sinkhorn scratch ----------------
// grid (6, 100): block = 256 u's for one w. Coalesced D2PT reads, scattered (4B) Kmat writes.
__global__ __launch_bounds__(256) void k_expK(const float* __restrict__ D2PT, const float* __restrict__ musq,
                                              float* __restrict__ Kmat, float* __restrict__ cols,
                                              unsigned* __restrict__ misc_u) {
  int w = blockIdx.y;
  int u = blockIdx.x * 256 + threadIdx.x;
  if (blockIdx.x == 0 && w == 0) {
    for (int z = threadIdx.x; z < 9600; z += 256) cols[z] = 0.f;
    if (threadIdx.x < 16) misc_u[threadIdx.x] = 0u;
  }
  if (u < N_U) {
    float s = 0.f;
#pragma unroll
    for (int sp = 0; sp < G1_SPLIT; ++sp) s += D2PT[(size_t)sp * D2P_STRIDE + (size_t)w * 1536 + u];
    float d2 = 1.0f + musq[w] - 2.0f * s;
    Kmat[(size_t)u * WAY + w] = expf(-LAMF * sqrtf(fmaxf(d2, 1e-12f)));
  }
}

// ---------------- sinkhorn (single kernel, device-scope barrier) ----------------
__device__ __forceinline__ void grid_barrier(unsigned* cnt, unsigned* gen, unsigned nb) {
  __syncthreads();
  if (threadIdx.x == 0) {
    __threadfence();
    unsigned g = __hip_atomic_load(gen, __ATOMIC_RELAXED, __HIP_MEMORY_SCOPE_AGENT);
    unsigned a = __hip_atomic_fetch_add(cnt, 1u, __ATOMIC_ACQ_REL, __HIP_MEMORY_SCOPE_AGENT);
    if (a == nb - 1u) {
      __hip_atomic_store(cnt, 0u, __ATOMIC_RELAXED, __HIP_MEMORY_SCOPE_AGENT);
      __hip_atomic_fetch_add(gen, 1u, __ATOMIC_RELEASE, __HIP_MEMORY_SCOPE_AGENT);
    } else {
      while (__hip_atomic_load(gen, __ATOMIC_ACQUIRE, __HIP_MEMORY_SCOPE_AGENT) == g) {
        __builtin_amdgcn_s_sleep(1);
      }
    }
    __threadfence();
  }
  __syncthreads();
}

__global__ __launch_bounds__(256) void k_sink(const float* __restrict__ Kg, float* __restrict__ Pg,
                                              float* __restrict__ cols, unsigned* __restrict__ misc_u,
                                              float* __restrict__ misc_f) {
  __shared__ float Kl[RPB * WAY];                // 37.6 KB
  __shared__ float a[RPB], aold[RPB], prevs[RPB], b[WAY];
  __shared__ float rerr[256];
  __shared__ float c2[2 * WAY];
  __shared__ float red[256];
  unsigned* errG = misc_u;
  float* KsumG = misc_f + 3;
  unsigned* cnt = misc_u + 4;
  unsigned* gen = misc_u + 5;
  int tid = threadIdx.x;
  int row0 = blockIdx.x * RPB;
  int nrows = (row0 + RPB <= N_U) ? RPB : (N_U - row0);   // last block: 90

  float ks = 0.f;
  for (int idx = tid; idx < nrows * WAY; idx += 256) { float v = Kg[row0 * WAY + idx]; Kl[idx] = v; ks += v; }
  red[tid] = ks; __syncthreads();
  for (int o = 128; o > 0; o >>= 1) { if (tid < o) red[tid] += red[tid + o]; __syncthreads(); }
  if (tid == 0) atomicAdd(KsumG, red[0]);
  if (tid < RPB) prevs[tid] = 0.f;
  if (tid < WAY) b[tid] = 1.0f;
  grid_barrier(cnt, gen, SINK_BLOCKS);
  float S = *KsumG;
  if (tid < RPB) a[tid] = 1.0f / S;   // folds K/K.sum() into a exactly

  bool conv = false;
  for (int t = 0; t < MAXIT; ++t) {
    int buf = t % 3;
    int zb = (t + 1) % 3;
    __syncthreads();                       // b stable from previous readback
    if (tid < nrows) {
      const float* kr = &Kl[tid * WAY];
      float r0 = 0.f, r1 = 0.f, r2 = 0.f, r3 = 0.f;
#pragma unroll 4
      for (int j = 0; j < WAY; j += 4) {
        r0 = fmaf(kr[j], b[j], r0);
        r1 = fmaf(kr[j + 1], b[j + 1], r1);
        r2 = fmaf(kr[j + 2], b[j + 2], r2);
        r3 = fmaf(kr[j + 3], b[j + 3], r3);
      }
      float rs = ((r0 + r1) + (r2 + r3)) * a[tid];
      rerr[tid] = fabsf(prevs[tid] - rs);
      aold[tid] = a[tid];
      a[tid] = a[tid] / rs;                // speculative; rolled back on convergence
      prevs[tid] = rs;
    } else {
      rerr[tid] = 0.f;
    }
    __syncthreads();                       // new a[] + rerr complete
    {
      int j = -1, rlo = 0, rhi = 0, slot = 0;
      if (tid < WAY) { j = tid; rlo = 0; rhi = 47; slot = 0; }
      else if (tid >= 128 && tid < 128 + WAY) { j = tid - 128; rlo = 47; rhi = RPB; slot = 1; }
      if (j >= 0) {
        if (rhi > nrows) rhi = nrows;
        float pc = 0.f;
        for (int r = rlo; r < rhi; ++r) pc = fmaf(Kl[r * WAY + j], a[r], pc);
        c2[slot * WAY + j] = pc;
      }
    }
    __syncthreads();
    if (tid < WAY) atomicAdd(&cols[buf * 3200 + tid * 32], c2[tid] + c2[WAY + tid]);
    if (blockIdx.x == 0) {
      if (tid < WAY) cols[zb * 3200 + tid * 32] = 0.f;   // safe: last read 2 barriers ago
      if (tid == 0) __hip_atomic_store(&errG[zb], 0u, __ATOMIC_RELAXED, __HIP_MEMORY_SCOPE_AGENT);
    }
    if (tid < 64) {
      float m = fmaxf(fmaxf(rerr[tid], rerr[tid + 64]), fmaxf(rerr[tid + 128], rerr[tid + 192]));
#pragma unroll
      for (int o = 32; o > 0; o >>= 1) m = fmaxf(m, __shfl_down(m, o));
      if (tid == 0) atomicMax(&errG[buf], __float_as_uint(m));
    }
    grid_barrier(cnt, gen, SINK_BLOCKS);
    unsigned eu = __hip_atomic_load(&errG[buf], __ATOMIC_RELAXED, __HIP_MEMORY_SCOPE_AGENT);
    if (__uint_as_float(eu) <= EPSF) { conv = true; break; }
    if (tid < WAY) b[tid] = (float)NQ / cols[buf * 3200 + tid * 32];
  }
  __syncthreads();
  for (int idx = tid; idx < nrows * WAY; idx += 256) {
    int r = idx / WAY; int j = idx - r * WAY;
    float av = conv ? aold[r] : a[r];
    Pg[row0 * WAY + idx] = av * Kl[idx] * b[j];
  }
}

// ---------------- GEMM2: CP[us] += Pu^T x Zu (split over u) ----------------
__global__ __launch_bounds__(256) void k_gemm2(const float* __restrict__ P, const float* __restrict__ Zu,
                                               float* __restrict__ CP) {
  int k = blockIdx.x * 256 + threadIdx.x;   // 16 * 256 = 4096
  int w0 = blockIdx.y * 10;                 // 10 blocks
  int u0 = blockIdx.z * 375;                // 4 splits
  __shared__ __align__(16) float Pl[75][12];
  float acc[10];
#pragma unroll
  for (int c = 0; c < 10; ++c) acc[c] = 0.f;
  for (int ch = 0; ch < 5; ++ch) {
    int ub = u0 + ch * 75;
    __syncthreads();
    for (int idx = threadIdx.x; idx < 750; idx += 256) {
      int uu = idx / 10, cc = idx - uu * 10;
      Pl[uu][cc] = P[(size_t)(ub + uu) * WAY + w0 + cc];
    }
    __syncthreads();
    for (int u = 0; u < 75; ++u) {
      float z = Zu[(size_t)(ub + u) * DD + k];
      const float* pr = &Pl[u][0];
      const float4 p0 = *(const float4*)pr;
      const float4 p1 = *(const float4*)(pr + 4);
      const float2 p2 = *(const float2*)(pr + 8);
      acc[0] = fmaf(p0.x, z, acc[0]); acc[1] = fmaf(p0.y, z, acc[1]);
      acc[2] = fmaf(p0.z, z, acc[2]); acc[3] = fmaf(p0.w, z, acc[3]);
      acc[4] = fmaf(p1.x, z, acc[4]); acc[5] = fmaf(p1.y, z, acc[5]);
      acc[6] = fmaf(p1.z, z, acc[6]); acc[7] = fmaf(p1.w, z, acc[7]);
      acc[8] = fmaf(p2.x, z, acc[8]); acc[9] = fmaf(p2.y, z, acc[9]);
    }
  }
  float* dst = CP + (size_t)blockIdx.z * CP_STRIDE;
#pragma unroll
  for (int c = 0; c < 10; ++c) dst[(size_t)(w0 + c) * DD + k] = acc[c];
}

// ---------------- mus update + musq (+ bf16 mus for gemm1) ----------------
__global__ __launch_bounds__(256) void k_musup(const float* __restrict__ musR, const float* __restrict__ SL,
                                               const float* __restrict__ CP, float* __restrict__ musW,
                                               float* __restrict__ musq, short* __restrict__ musb) {
  int w = blockIdx.x, tid = threadIdx.x;
  __shared__ float red[256];
  float q = 0.f;
  for (int k = tid; k < DD; k += 256) {
    size_t o = (size_t)w * DD + k;
    float c2 = CP[o] + CP[CP_STRIDE + o] + CP[2 * CP_STRIDE + o] + CP[3 * CP_STRIDE + o];
    float emus = (SL[o] + c2) / 20.0f;   // p.sum(0) == 5 + 15 exactly
    float m = musR[o];
    float v = m + 0.2f * (emus - m);
    musW[o] = v;
    musb[o] = f2bs(v);
    q += v * v;
  }
  red[tid] = q; __syncthreads();
  for (int o = 128; o > 0; o >>= 1) { if (tid < o) red[tid] += red[tid + o]; __syncthreads(); }
  if (tid == 0) musq[w] = red[0];
}

// ---------------- final logP + acc ----------------
__global__ __launch_bounds__(128) void k_final(const float* __restrict__ Pg, const int* __restrict__ labels,
                                               float* __restrict__ out, unsigned* __restrict__ ctr) {
  int u = blockIdx.x, tid = threadIdx.x;
  __shared__ float vals[WAY];
  if (tid < WAY) {
    float v = Pg[(size_t)u * WAY + tid];
    vals[tid] = v;
    out[(size_t)u * WAY + tid] = logf(v + 1e-5f);
  }
  __syncthreads();
  if (tid == 0) {
    int am = 0; float bv = vals[0];
    for (int j = 1; j < WAY; ++j) { if (vals[j] > bv) { bv = vals[j]; am = j; } }
    if (am == labels[N_L + u]) atomicAdd(ctr, 1u);
  }
}

__global__ void k_acc(const unsigned* __restrict__ ctr, float* __restrict__ out) {
  if (threadIdx.x == 0) out[N_U * WAY] = (float)(*ctr) / 1500.0f;
}

// ---------------- host ----------------
extern "C" void kernel_launch(void* const* d_in, const int* in_sizes, int n_in,
                              void* d_out, int out_size, void* d_ws, size_t ws_size,
                              hipStream_t stream) {
  const float* X = (const float*)d_in[0];
  const int* labels = (const int*)d_in[1];
  float* out = (float*)d_out;
  float* ws = (float*)d_ws;

  float* Z     = ws + OFF_Z;
  float* Zu    = Z + (size_t)N_L * DD;
  float* meanL = ws + OFF_MEANL;
  float* meanU = ws + OFF_MEANU;
  float* SL    = ws + OFF_SL;
  float* musA  = ws + OFF_MUSA;
  float* musB  = ws + OFF_MUSB;
  float* musq  = ws + OFF_MUSQ;
  float* Kmat  = ws + OFF_KMAT;
  short* musb16 = (short*)(ws + OFF_MUSB16);
  float* Pmat  = ws + OFF_PMAT;
  float* cols  = ws + OFF_COLS;
  float* misc_f = ws + OFF_MISC;
  unsigned* misc_u = (unsigned*)(ws + OFF_MISC);
  float* D2PT  = ws + OFF_D2P;
  float* CP    = ws + OFF_D2P;   // overlaid: disjoint lifetimes within an epoch

  k_pow_norm<<<N_TOT, 256, 0, stream>>>(X, Z, meanL);
  k_colmeans<<<dim3(16, 25), 256, 0, stream>>>(Z, meanL, meanU);
  k_center<<<N_TOT, 256, 0, stream>>>(Z, meanL, meanU);
  k_musinit<<<WAY, 256, 0, stream>>>(Z, SL, musA, musq, musb16);

  float* musR = musA;
  float* musW = musB;
  for (int e = 0; e < 20; ++e) {
    k_gemm1<<<dim3(24, G1_SPLIT), 256, 0, stream>>>(Zu, musb16, D2PT);
    k_expK<<<dim3(6, WAY), 256, 0, stream>>>(D2PT, musq, Kmat, cols, misc_u);
    k_sink<<<SINK_BLOCKS, 256, 0, stream>>>(Kmat, Pmat, cols, misc_u, misc_f);
    k_gemm2<<<dim3(16, 10, 4), 256, 0, stream>>>(Pmat, Zu, CP);
    k_musup<<<WAY, 256, 0, stream>>>(musR, SL, CP, musW, musq, musb16);
    float* tmp = musR; musR = musW; musW = tmp;
  }
  k_gemm1<<<dim3(24, G1_SPLIT), 256, 0, stream>>>(Zu, musb16, D2PT);
  k_expK<<<dim3(6, WAY), 256, 0, stream>>>(D2PT, musq, Kmat, cols, misc_u);
  k_sink<<<SINK_BLOCKS, 256, 0, stream>>>(Kmat, Pmat, cols, misc_u, misc_f);
  k_final<<<N_U, 128, 0, stream>>>(Pmat, labels, out, misc_u + 6);
  k_acc<<<1, 64, 0, stream>>>(misc_u + 6, out);
}